// Round 6
// baseline (268.855 us; speedup 1.0000x reference)
//
#include <hip/hip_runtime.h>
#include <hip/hip_bf16.h>

typedef short v8s __attribute__((ext_vector_type(8)));
typedef short v4s __attribute__((ext_vector_type(4)));
typedef float v4f __attribute__((ext_vector_type(4)));

#define BS 4
#define SEQ 2048
#define DMODEL 768
#define HEADS 12
#define GROUPS 2
#define DK 64
#define LOG2E 1.4426950408889634f

static __device__ __forceinline__ short f2bs(float f) {
    __hip_bfloat16 h = __float2bfloat16(f);
    return *reinterpret_cast<short*>(&h);
}

static __device__ __forceinline__ float fast_exp2(float x) {
#if __has_builtin(__builtin_amdgcn_exp2f)
    return __builtin_amdgcn_exp2f(x);
#else
    return __expf(x * 0.6931471805599453f);
#endif
}

struct alignas(8) s4pack { short a, b, c, d; };

// ---------------------------------------------------------------------------
// q fp32 -> bf16 (Q A-matrix is re-read 6x by proj slices; k/v read once so
// they stay fp32). grid 1536 x 256.
// ---------------------------------------------------------------------------
__global__ __launch_bounds__(256) void convert_q(
    const float* __restrict__ q, short* __restrict__ qbf)
{
    const size_t base = (size_t)blockIdx.x * 4096;
#pragma unroll
    for (int r = 0; r < 4; ++r) {
        const size_t i = base + r * 1024 + threadIdx.x * 4;
        const float4 a = *reinterpret_cast<const float4*>(q + i);
        s4pack p{f2bs(a.x), f2bs(a.y), f2bs(a.z), f2bs(a.w)};
        *reinterpret_cast<s4pack*>(qbf + i) = p;
    }
}

// ---------------------------------------------------------------------------
// Fused weight transpose + fp32->bf16. z: 0=Wq 1=Wo 2=Wk 3=Wv. grid (24,24,4).
// ---------------------------------------------------------------------------
__global__ __launch_bounds__(256) void wtrans_all(
    const float* __restrict__ Wq, const float* __restrict__ Wk,
    const float* __restrict__ Wv, const float* __restrict__ Wo,
    short* __restrict__ WqT, short* __restrict__ WkT,
    short* __restrict__ WvT, short* __restrict__ WoT)
{
    const int z = blockIdx.z;
    const float* W;
    short* WT;
    int N;
    if (z == 0)      { W = Wq; WT = WqT; N = 768; }
    else if (z == 1) { W = Wo; WT = WoT; N = 768; }
    else if (z == 2) { W = Wk; WT = WkT; N = 128; }
    else             { W = Wv; WT = WvT; N = 128; }
    const int n0 = blockIdx.x * 32, k0 = blockIdx.y * 32;
    if (n0 >= N) return;

    __shared__ float t[32][33];
    const int lx = threadIdx.x & 31, ly = threadIdx.x >> 5;
#pragma unroll
    for (int r = 0; r < 4; ++r)
        t[ly + r * 8][lx] = W[(size_t)(k0 + ly + r * 8) * N + n0 + lx];
    __syncthreads();
#pragma unroll
    for (int r = 0; r < 4; ++r)
        WT[(size_t)(n0 + ly + r * 8) * DMODEL + k0 + lx] = f2bs(t[lx][ly + r * 8]);
}

// ---------------------------------------------------------------------------
// Unified projection, BM=128/BN=128/BK=32; 4 waves 2x2 (wave 64x64, 16
// MFMA/iter). grid (64, 8): y<6 Q slice y (bf16 A, *log2e); y==6 K; y==7 V
// (transposed + s-permuted within 64-token blocks for attn's K=32 PV).
// ---------------------------------------------------------------------------
__global__ __launch_bounds__(256) void proj_all(
    const short* __restrict__ qbf, const float* __restrict__ kin,
    const float* __restrict__ vin,
    const short* __restrict__ WqT, const short* __restrict__ WkT,
    const short* __restrict__ WvT,
    const float* __restrict__ bq, const float* __restrict__ bk,
    const float* __restrict__ bv,
    short* __restrict__ Qp, short* __restrict__ Kp, short* __restrict__ Vt)
{
    const int LS = 40;
    __shared__ short lA[128 * 40];
    __shared__ short lB[128 * 40];

    const int y = blockIdx.y;
    const short* WT = (y < 6) ? WqT + (size_t)y * 128 * DMODEL
                              : (y == 6) ? WkT : WvT;
    const float* bias = (y < 6) ? bq + y * 128 : (y == 6) ? bk : bv;

    const int tid  = threadIdx.x;
    const int lane = tid & 63;
    const int wid  = tid >> 6;
    const int l16  = lane & 15;
    const int quad = lane >> 4;
    const int wm   = wid & 1;
    const int wn   = wid >> 1;
    const int bm   = blockIdx.x;

    v4f acc[4][4];
#pragma unroll
    for (int i = 0; i < 4; ++i)
#pragma unroll
        for (int j = 0; j < 4; ++j) acc[i][j] = (v4f){0.f, 0.f, 0.f, 0.f};

    for (int kt = 0; kt < 24; ++kt) {
        const int k0 = kt * 32;
        if (y < 6) {
            // bf16 A: 128x32, b128 copies
#pragma unroll
            for (int r = 0; r < 2; ++r) {
                int idx = tid + 256 * r;
                int row = idx >> 2, c8 = (idx & 3) << 3;
                *reinterpret_cast<v8s*>(&lA[row * LS + c8]) =
                    *reinterpret_cast<const v8s*>(qbf + (size_t)(bm * 128 + row) * DMODEL + k0 + c8);
            }
        } else {
            const float* A = (y == 6) ? kin : vin;
#pragma unroll
            for (int r = 0; r < 4; ++r) {
                int f4  = tid + 256 * r;
                int row = f4 >> 3;
                int c4  = (f4 & 7) << 2;
                const float4 a = *reinterpret_cast<const float4*>(
                    A + (size_t)(bm * 128 + row) * DMODEL + k0 + c4);
                s4pack p{f2bs(a.x), f2bs(a.y), f2bs(a.z), f2bs(a.w)};
                *reinterpret_cast<s4pack*>(&lA[row * LS + c4]) = p;
            }
        }
#pragma unroll
        for (int r = 0; r < 2; ++r) {
            int idx = tid + 256 * r;
            int row = idx >> 2, c8 = (idx & 3) << 3;
            *reinterpret_cast<v8s*>(&lB[row * LS + c8]) =
                *reinterpret_cast<const v8s*>(WT + (size_t)row * DMODEL + k0 + c8);
        }
        __syncthreads();

        v8s af[4], bf[4];
#pragma unroll
        for (int i = 0; i < 4; ++i)
            af[i] = *reinterpret_cast<const v8s*>(&lA[(wm * 64 + i * 16 + l16) * LS + quad * 8]);
#pragma unroll
        for (int j = 0; j < 4; ++j)
            bf[j] = *reinterpret_cast<const v8s*>(&lB[(wn * 64 + j * 16 + l16) * LS + quad * 8]);
#pragma unroll
        for (int i = 0; i < 4; ++i)
#pragma unroll
            for (int j = 0; j < 4; ++j)
                acc[i][j] = __builtin_amdgcn_mfma_f32_16x16x32_bf16(af[i], bf[j], acc[i][j], 0, 0, 0);
        __syncthreads();
    }

#pragma unroll
    for (int i = 0; i < 4; ++i) {
#pragma unroll
        for (int j = 0; j < 4; ++j) {
            const int Cl = wn * 64 + j * 16 + l16;   // 0..127 within slice
            const float bvv = bias[Cl];
#pragma unroll
            for (int reg = 0; reg < 4; ++reg) {
                const int R = bm * 128 + wm * 64 + i * 16 + quad * 4 + reg;
                const int b = R >> 11;
                const int s = R & 2047;
                if (y < 6) {
                    const int C = y * 128 + Cl;
                    const int h = C >> 6, d = C & 63;
                    Qp[((size_t)(b * HEADS + h) * SEQ + s) * DK + d] =
                        f2bs((acc[i][j][reg] + bvv) * LOG2E);
                } else if (y == 6) {
                    const int g = Cl >> 6, d = Cl & 63;
                    Kp[((size_t)(b * GROUPS + g) * SEQ + s) * DK + d] =
                        f2bs(acc[i][j][reg] + bvv);
                } else {
                    const int g = Cl >> 6, d = Cl & 63;
                    // k-permutation within each 64-token block (low 2 bits
                    // preserved -> 4 reg-consecutive stores still coalesce)
                    const int s2 = (s & ~63) | (s & 0x23) | ((s & 0x0C) << 1) | ((s & 0x10) >> 2);
                    Vt[((size_t)(b * GROUPS + g) * DK + d) * SEQ + s2] =
                        f2bs(acc[i][j][reg] + bvv);
                }
            }
        }
    }
}

// ---------------------------------------------------------------------------
// Flash attention, no-max softmax, S^T trick + K=32 PV (V pre-permuted in
// proj). BK=128: two 64-sub-tiles per barrier pair (halves barrier count).
// grid (16 qtiles, 12 heads, 4 batch), 256 thr = 4 waves, 32 q-rows/wave.
// LDS: lK 128x72 (18.4KB) + lV 64x136 (17.4KB) = 35.8KB -> 3 blocks/CU.
// ---------------------------------------------------------------------------
__global__ __launch_bounds__(256) void attn_kernel(
    const short* __restrict__ Qp, const short* __restrict__ Kp,
    const short* __restrict__ Vt, short* __restrict__ Oat)
{
    const int LSK = 72;    // 144 B stride = 4 mod 32 banks -> 2-way only
    const int LSV = 136;   // 272 B stride = 4 mod 32 banks -> 2-way only
    __shared__ short lK[128 * 72];   // [k_row][d]
    __shared__ short lV[64 * 136];   // [d][k_col permuted]

    const int qt = blockIdx.x, h = blockIdx.y, b = blockIdx.z;
    const int g = h & 1;
    const int tid  = threadIdx.x;
    const int lane = tid & 63;
    const int wid  = tid >> 6;
    const int l16  = lane & 15;
    const int quad = lane >> 4;

    v8s qf[2][2];
#pragma unroll
    for (int mi = 0; mi < 2; ++mi) {
        const size_t qbase =
            ((size_t)(b * HEADS + h) * SEQ + qt * 128 + wid * 32 + mi * 16 + l16) * DK;
        qf[mi][0] = *reinterpret_cast<const v8s*>(Qp + qbase + quad * 8);
        qf[mi][1] = *reinterpret_cast<const v8s*>(Qp + qbase + quad * 8 + 32);
    }

    const size_t kbase = (size_t)(b * GROUPS + g) * SEQ * DK;
    const size_t vbase = (size_t)(b * GROUPS + g) * DK * SEQ;

    const short one = (short)0x3F80;
    const v8s ones8 = {one, one, one, one, one, one, one, one};

    v4f oacc[2][5];
#pragma unroll
    for (int mi = 0; mi < 2; ++mi)
#pragma unroll
        for (int n = 0; n < 5; ++n) oacc[mi][n] = (v4f){0.f, 0.f, 0.f, 0.f};

    for (int kt = 0; kt < 16; ++kt) {
        // stage K [128][64] natural; V^T [64][128] (cols pre-permuted)
#pragma unroll
        for (int r = 0; r < 4; ++r) {
            const int idx = tid + 256 * r;
            const int rowK = idx >> 3, cK = (idx & 7) << 3;
            *reinterpret_cast<v8s*>(&lK[rowK * LSK + cK]) =
                *reinterpret_cast<const v8s*>(Kp + kbase + (size_t)(kt * 128 + rowK) * DK + cK);
            const int rowV = idx >> 4, cV = (idx & 15) << 3;
            *reinterpret_cast<v8s*>(&lV[rowV * LSV + cV]) =
                *reinterpret_cast<const v8s*>(Vt + vbase + (size_t)rowV * SEQ + kt * 128 + cV);
        }
        __syncthreads();

#pragma unroll
        for (int kt2 = 0; kt2 < 2; ++kt2) {
            // S^T = K Q^T per 16-k block; P = exp2 packed to bf16 in regs
            v4s pp[2][4];
#pragma unroll
            for (int j = 0; j < 4; ++j) {
                const v8s kf0 = *reinterpret_cast<const v8s*>(
                    &lK[(kt2 * 64 + j * 16 + l16) * LSK + quad * 8]);
                const v8s kf1 = *reinterpret_cast<const v8s*>(
                    &lK[(kt2 * 64 + j * 16 + l16) * LSK + quad * 8 + 32]);
#pragma unroll
                for (int mi = 0; mi < 2; ++mi) {
                    v4f z = (v4f){0.f, 0.f, 0.f, 0.f};
                    z = __builtin_amdgcn_mfma_f32_16x16x32_bf16(kf0, qf[mi][0], z, 0, 0, 0);
                    z = __builtin_amdgcn_mfma_f32_16x16x32_bf16(kf1, qf[mi][1], z, 0, 0, 0);
                    v4s p;
#pragma unroll
                    for (int reg = 0; reg < 4; ++reg) p[reg] = f2bs(fast_exp2(z[reg]));
                    pp[mi][j] = p;
                }
            }

            // O += P V via K=32 MFMAs; ones-frag = rowsum
#pragma unroll
            for (int cj = 0; cj < 2; ++cj) {
                v8s pf[2];
#pragma unroll
                for (int mi = 0; mi < 2; ++mi)
                    pf[mi] = __builtin_shufflevector(pp[mi][2 * cj], pp[mi][2 * cj + 1],
                                                     0, 1, 2, 3, 4, 5, 6, 7);
#pragma unroll
                for (int n = 0; n < 4; ++n) {
                    const v8s vf = *reinterpret_cast<const v8s*>(
                        &lV[(n * 16 + l16) * LSV + kt2 * 64 + cj * 32 + quad * 8]);
#pragma unroll
                    for (int mi = 0; mi < 2; ++mi)
                        oacc[mi][n] = __builtin_amdgcn_mfma_f32_16x16x32_bf16(pf[mi], vf, oacc[mi][n], 0, 0, 0);
                }
#pragma unroll
                for (int mi = 0; mi < 2; ++mi)
                    oacc[mi][4] = __builtin_amdgcn_mfma_f32_16x16x32_bf16(pf[mi], ones8, oacc[mi][4], 0, 0, 0);
            }
        }
        __syncthreads();
    }

    // epilogue: every lane of the ones-tile holds its own rowsum
#pragma unroll
    for (int mi = 0; mi < 2; ++mi) {
        float rdiv[4];
#pragma unroll
        for (int reg = 0; reg < 4; ++reg)
            rdiv[reg] = __builtin_amdgcn_rcpf(oacc[mi][4][reg]);
#pragma unroll
        for (int n = 0; n < 4; ++n)
#pragma unroll
            for (int reg = 0; reg < 4; ++reg) {
                const int qrow = qt * 128 + wid * 32 + mi * 16 + quad * 4 + reg;
                Oat[(size_t)(b * SEQ + qrow) * DMODEL + h * 64 + n * 16 + l16] =
                    f2bs(oacc[mi][n][reg] * rdiv[reg]);
            }
    }
}

// ---------------------------------------------------------------------------
// Output GEMM: out[8192,768] = Oat(bf16) @ WoT^T + bo, fp32.
// BM=64, BN=128: grid (128,6) = 768 blocks = 3/CU.
// ---------------------------------------------------------------------------
__global__ __launch_bounds__(256) void out_gemm(
    const short* __restrict__ A, const short* __restrict__ WT,
    const float* __restrict__ bias, float* __restrict__ out)
{
    const int LS = 40;
    __shared__ short lA[64 * 40];
    __shared__ short lB[128 * 40];

    const int tid  = threadIdx.x;
    const int lane = tid & 63;
    const int wid  = tid >> 6;
    const int l16  = lane & 15;
    const int quad = lane >> 4;
    const int wm   = wid & 1;
    const int wn   = wid >> 1;
    const int bm   = blockIdx.x;
    const int bn   = blockIdx.y;

    v4f acc[2][4];
#pragma unroll
    for (int i = 0; i < 2; ++i)
#pragma unroll
        for (int j = 0; j < 4; ++j) acc[i][j] = (v4f){0.f, 0.f, 0.f, 0.f};

    for (int kt = 0; kt < 24; ++kt) {
        const int k0 = kt * 32;
        {
            const int row = tid >> 2, c8 = (tid & 3) << 3;
            *reinterpret_cast<v8s*>(&lA[row * LS + c8]) =
                *reinterpret_cast<const v8s*>(A + (size_t)(bm * 64 + row) * DMODEL + k0 + c8);
        }
#pragma unroll
        for (int r = 0; r < 2; ++r) {
            int idx = tid + 256 * r;
            int row = idx >> 2, c8 = (idx & 3) << 3;
            *reinterpret_cast<v8s*>(&lB[row * LS + c8]) =
                *reinterpret_cast<const v8s*>(WT + (size_t)(bn * 128 + row) * DMODEL + k0 + c8);
        }
        __syncthreads();

        v8s af[2], bf[4];
#pragma unroll
        for (int i = 0; i < 2; ++i)
            af[i] = *reinterpret_cast<const v8s*>(&lA[(wm * 32 + i * 16 + l16) * LS + quad * 8]);
#pragma unroll
        for (int j = 0; j < 4; ++j)
            bf[j] = *reinterpret_cast<const v8s*>(&lB[(wn * 64 + j * 16 + l16) * LS + quad * 8]);
#pragma unroll
        for (int i = 0; i < 2; ++i)
#pragma unroll
            for (int j = 0; j < 4; ++j)
                acc[i][j] = __builtin_amdgcn_mfma_f32_16x16x32_bf16(af[i], bf[j], acc[i][j], 0, 0, 0);
        __syncthreads();
    }

#pragma unroll
    for (int i = 0; i < 2; ++i)
#pragma unroll
        for (int j = 0; j < 4; ++j) {
            const int C = bn * 128 + wn * 64 + j * 16 + l16;
            const float bv = bias[C];
#pragma unroll
            for (int reg = 0; reg < 4; ++reg) {
                const int R = bm * 64 + wm * 32 + i * 16 + quad * 4 + reg;
                out[(size_t)R * DMODEL + C] = acc[i][j][reg] + bv;
            }
        }
}

extern "C" void kernel_launch(void* const* d_in, const int* in_sizes, int n_in,
                              void* d_out, int out_size, void* d_ws, size_t ws_size,
                              hipStream_t stream) {
    const float* q  = (const float*)d_in[0];
    const float* k  = (const float*)d_in[1];
    const float* v  = (const float*)d_in[2];
    const float* Wq = (const float*)d_in[3];
    const float* bq = (const float*)d_in[4];
    const float* Wk = (const float*)d_in[5];
    const float* bk = (const float*)d_in[6];
    const float* Wv = (const float*)d_in[7];
    const float* bv = (const float*)d_in[8];
    const float* Wo = (const float*)d_in[9];
    const float* bo = (const float*)d_in[10];

    short* WqT = (short*)d_ws;                              // 589824
    short* WkT = WqT + 589824;                              // 98304
    short* WvT = WkT + 98304;                               // 98304
    short* WoT = WvT + 98304;                               // 589824
    short* qbf = WoT + 589824;                              // 6291456
    short* Qp  = qbf + 6291456;                             // [b,h,s,d]  6291456
    short* Kp  = Qp + (size_t)BS * HEADS * SEQ * DK;        // [b,g,s,d]  1048576
    short* Vt  = Kp + (size_t)BS * GROUPS * SEQ * DK;       // [b,g,d,s_perm] 1048576
    short* Oat = Vt + (size_t)BS * GROUPS * SEQ * DK;       // [b,s,h*d]  6291456

    convert_q<<<1536, 256, 0, stream>>>(q, qbf);
    wtrans_all<<<dim3(24, 24, 4), 256, 0, stream>>>(Wq, Wk, Wv, Wo, WqT, WkT, WvT, WoT);
    proj_all<<<dim3(64, 8), 256, 0, stream>>>(qbf, k, v, WqT, WkT, WvT,
                                              bq, bk, bv, Qp, Kp, Vt);
    attn_kernel<<<dim3(16, HEADS, BS), 256, 0, stream>>>(Qp, Kp, Vt, Oat);
    out_gemm<<<dim3(128, 6), 256, 0, stream>>>(Oat, WoT, bo, (float*)d_out);
}

// Round 7
// 256.886 us; speedup vs baseline: 1.0466x; 1.0466x over previous
//
#include <hip/hip_runtime.h>
#include <hip/hip_bf16.h>

typedef short v8s __attribute__((ext_vector_type(8)));
typedef short v4s __attribute__((ext_vector_type(4)));
typedef float v4f __attribute__((ext_vector_type(4)));

#define BS 4
#define SEQ 2048
#define DMODEL 768
#define HEADS 12
#define GROUPS 2
#define DK 64
#define LOG2E 1.4426950408889634f

static __device__ __forceinline__ short f2bs(float f) {
    __hip_bfloat16 h = __float2bfloat16(f);
    return *reinterpret_cast<short*>(&h);
}

static __device__ __forceinline__ float fast_exp2(float x) {
#if __has_builtin(__builtin_amdgcn_exp2f)
    return __builtin_amdgcn_exp2f(x);
#else
    return __expf(x * 0.6931471805599453f);
#endif
}

// Async global->LDS, 16B per lane. LDS dest is WAVE-UNIFORM base; lane i's
// 16B lands at base + i*16 (m97 semantics). Requires unpadded lane-contiguous
// LDS chunks.
static __device__ __forceinline__ void gld16(const short* g, short* l) {
    __builtin_amdgcn_global_load_lds(
        (__attribute__((address_space(1))) void*)(g),
        (__attribute__((address_space(3))) void*)(l), 16, 0, 0);
}

struct alignas(8) s4pack { short a, b, c, d; };

// ---------------------------------------------------------------------------
// q fp32 -> bf16. grid 1536 x 256.
// ---------------------------------------------------------------------------
__global__ __launch_bounds__(256) void convert_q(
    const float* __restrict__ q, short* __restrict__ qbf)
{
    const size_t base = (size_t)blockIdx.x * 4096;
#pragma unroll
    for (int r = 0; r < 4; ++r) {
        const size_t i = base + r * 1024 + threadIdx.x * 4;
        const float4 a = *reinterpret_cast<const float4*>(q + i);
        s4pack p{f2bs(a.x), f2bs(a.y), f2bs(a.z), f2bs(a.w)};
        *reinterpret_cast<s4pack*>(qbf + i) = p;
    }
}

// ---------------------------------------------------------------------------
// Fused weight transpose + fp32->bf16. z: 0=Wq 1=Wo 2=Wk 3=Wv. grid (24,24,4).
// ---------------------------------------------------------------------------
__global__ __launch_bounds__(256) void wtrans_all(
    const float* __restrict__ Wq, const float* __restrict__ Wk,
    const float* __restrict__ Wv, const float* __restrict__ Wo,
    short* __restrict__ WqT, short* __restrict__ WkT,
    short* __restrict__ WvT, short* __restrict__ WoT)
{
    const int z = blockIdx.z;
    const float* W;
    short* WT;
    int N;
    if (z == 0)      { W = Wq; WT = WqT; N = 768; }
    else if (z == 1) { W = Wo; WT = WoT; N = 768; }
    else if (z == 2) { W = Wk; WT = WkT; N = 128; }
    else             { W = Wv; WT = WvT; N = 128; }
    const int n0 = blockIdx.x * 32, k0 = blockIdx.y * 32;
    if (n0 >= N) return;

    __shared__ float t[32][33];
    const int lx = threadIdx.x & 31, ly = threadIdx.x >> 5;
#pragma unroll
    for (int r = 0; r < 4; ++r)
        t[ly + r * 8][lx] = W[(size_t)(k0 + ly + r * 8) * N + n0 + lx];
    __syncthreads();
#pragma unroll
    for (int r = 0; r < 4; ++r)
        WT[(size_t)(n0 + ly + r * 8) * DMODEL + k0 + lx] = f2bs(t[lx][ly + r * 8]);
}

// ---------------------------------------------------------------------------
// Unified projection, m97-style: BM=BN=128, BK=32, unpadded [128][32] LDS
// tiles staged via global_load_lds (bf16 sources) or VGPR-convert (fp32 k/v).
// grid (64, 8): y<6 Q slice y (*log2e); y==6 K; y==7 V (transposed +
// s-permuted within 64-token blocks for attn's K=32 PV).
// ---------------------------------------------------------------------------
__global__ __launch_bounds__(256) void proj_all(
    const short* __restrict__ qbf, const float* __restrict__ kin,
    const float* __restrict__ vin,
    const short* __restrict__ WqT, const short* __restrict__ WkT,
    const short* __restrict__ WvT,
    const float* __restrict__ bq, const float* __restrict__ bk,
    const float* __restrict__ bv,
    short* __restrict__ Qp, short* __restrict__ Kp, short* __restrict__ Vt)
{
    __shared__ short lA[128 * 32];
    __shared__ short lB[128 * 32];

    const int y = blockIdx.y;
    const short* WT = (y < 6) ? WqT + (size_t)y * 128 * DMODEL
                              : (y == 6) ? WkT : WvT;
    const float* bias = (y < 6) ? bq + y * 128 : (y == 6) ? bk : bv;

    const int tid  = threadIdx.x;
    const int lane = tid & 63;
    const int wid  = tid >> 6;
    const int l16  = lane & 15;
    const int quad = lane >> 4;
    const int wm   = wid & 1;
    const int wn   = wid >> 1;
    const int bm   = blockIdx.x;

    v4f acc[4][4];
#pragma unroll
    for (int i = 0; i < 4; ++i)
#pragma unroll
        for (int j = 0; j < 4; ++j) acc[i][j] = (v4f){0.f, 0.f, 0.f, 0.f};

    const int crow = lane >> 2;          // chunk-relative row 0..15
    const int ccol = (lane & 3) << 3;    // chunk-relative col (shorts)

    for (int kt = 0; kt < 24; ++kt) {
        const int k0 = kt * 32;
        if (y < 6) {
            const short* Ag = qbf + (size_t)bm * 128 * DMODEL + k0;
#pragma unroll
            for (int c = wid; c < 8; c += 4)
                gld16(Ag + (size_t)(c * 16 + crow) * DMODEL + ccol, &lA[c * 512]);
        } else {
            const float* A = (y == 6) ? kin : vin;
#pragma unroll
            for (int r = 0; r < 4; ++r) {
                int f4  = tid + 256 * r;
                int row = f4 >> 3;
                int c4  = (f4 & 7) << 2;
                const float4 a = *reinterpret_cast<const float4*>(
                    A + (size_t)(bm * 128 + row) * DMODEL + k0 + c4);
                s4pack p{f2bs(a.x), f2bs(a.y), f2bs(a.z), f2bs(a.w)};
                *reinterpret_cast<s4pack*>(&lA[row * 32 + c4]) = p;
            }
        }
        {
            const short* Bg = WT + k0;
#pragma unroll
            for (int c = wid; c < 8; c += 4)
                gld16(Bg + (size_t)(c * 16 + crow) * DMODEL + ccol, &lB[c * 512]);
        }
        __syncthreads();

        v8s af[4], bf[4];
#pragma unroll
        for (int i = 0; i < 4; ++i)
            af[i] = *reinterpret_cast<const v8s*>(&lA[(wm * 64 + i * 16 + l16) * 32 + quad * 8]);
#pragma unroll
        for (int j = 0; j < 4; ++j)
            bf[j] = *reinterpret_cast<const v8s*>(&lB[(wn * 64 + j * 16 + l16) * 32 + quad * 8]);
#pragma unroll
        for (int i = 0; i < 4; ++i)
#pragma unroll
            for (int j = 0; j < 4; ++j)
                acc[i][j] = __builtin_amdgcn_mfma_f32_16x16x32_bf16(af[i], bf[j], acc[i][j], 0, 0, 0);
        __syncthreads();
    }

#pragma unroll
    for (int i = 0; i < 4; ++i) {
#pragma unroll
        for (int j = 0; j < 4; ++j) {
            const int Cl = wn * 64 + j * 16 + l16;   // 0..127 within slice
            const float bvv = bias[Cl];
#pragma unroll
            for (int reg = 0; reg < 4; ++reg) {
                const int R = bm * 128 + wm * 64 + i * 16 + quad * 4 + reg;
                const int b = R >> 11;
                const int s = R & 2047;
                if (y < 6) {
                    const int C = y * 128 + Cl;
                    const int h = C >> 6, d = C & 63;
                    Qp[((size_t)(b * HEADS + h) * SEQ + s) * DK + d] =
                        f2bs((acc[i][j][reg] + bvv) * LOG2E);
                } else if (y == 6) {
                    const int g = Cl >> 6, d = Cl & 63;
                    Kp[((size_t)(b * GROUPS + g) * SEQ + s) * DK + d] =
                        f2bs(acc[i][j][reg] + bvv);
                } else {
                    const int g = Cl >> 6, d = Cl & 63;
                    const int s2 = (s & ~63) | (s & 0x23) | ((s & 0x0C) << 1) | ((s & 0x10) >> 2);
                    Vt[((size_t)(b * GROUPS + g) * DK + d) * SEQ + s2] =
                        f2bs(acc[i][j][reg] + bvv);
                }
            }
        }
    }
}

// ---------------------------------------------------------------------------
// Flash attention (unchanged from round 6): no-max softmax, S^T trick,
// K=32 PV on pre-permuted V, BK=128.
// ---------------------------------------------------------------------------
__global__ __launch_bounds__(256) void attn_kernel(
    const short* __restrict__ Qp, const short* __restrict__ Kp,
    const short* __restrict__ Vt, short* __restrict__ Oat)
{
    const int LSK = 72;
    const int LSV = 136;
    __shared__ short lK[128 * 72];
    __shared__ short lV[64 * 136];

    const int qt = blockIdx.x, h = blockIdx.y, b = blockIdx.z;
    const int g = h & 1;
    const int tid  = threadIdx.x;
    const int lane = tid & 63;
    const int wid  = tid >> 6;
    const int l16  = lane & 15;
    const int quad = lane >> 4;

    v8s qf[2][2];
#pragma unroll
    for (int mi = 0; mi < 2; ++mi) {
        const size_t qbase =
            ((size_t)(b * HEADS + h) * SEQ + qt * 128 + wid * 32 + mi * 16 + l16) * DK;
        qf[mi][0] = *reinterpret_cast<const v8s*>(Qp + qbase + quad * 8);
        qf[mi][1] = *reinterpret_cast<const v8s*>(Qp + qbase + quad * 8 + 32);
    }

    const size_t kbase = (size_t)(b * GROUPS + g) * SEQ * DK;
    const size_t vbase = (size_t)(b * GROUPS + g) * DK * SEQ;

    const short one = (short)0x3F80;
    const v8s ones8 = {one, one, one, one, one, one, one, one};

    v4f oacc[2][5];
#pragma unroll
    for (int mi = 0; mi < 2; ++mi)
#pragma unroll
        for (int n = 0; n < 5; ++n) oacc[mi][n] = (v4f){0.f, 0.f, 0.f, 0.f};

    for (int kt = 0; kt < 16; ++kt) {
#pragma unroll
        for (int r = 0; r < 4; ++r) {
            const int idx = tid + 256 * r;
            const int rowK = idx >> 3, cK = (idx & 7) << 3;
            *reinterpret_cast<v8s*>(&lK[rowK * LSK + cK]) =
                *reinterpret_cast<const v8s*>(Kp + kbase + (size_t)(kt * 128 + rowK) * DK + cK);
            const int rowV = idx >> 4, cV = (idx & 15) << 3;
            *reinterpret_cast<v8s*>(&lV[rowV * LSV + cV]) =
                *reinterpret_cast<const v8s*>(Vt + vbase + (size_t)rowV * SEQ + kt * 128 + cV);
        }
        __syncthreads();

#pragma unroll
        for (int kt2 = 0; kt2 < 2; ++kt2) {
            v4s pp[2][4];
#pragma unroll
            for (int j = 0; j < 4; ++j) {
                const v8s kf0 = *reinterpret_cast<const v8s*>(
                    &lK[(kt2 * 64 + j * 16 + l16) * LSK + quad * 8]);
                const v8s kf1 = *reinterpret_cast<const v8s*>(
                    &lK[(kt2 * 64 + j * 16 + l16) * LSK + quad * 8 + 32]);
#pragma unroll
                for (int mi = 0; mi < 2; ++mi) {
                    v4f z = (v4f){0.f, 0.f, 0.f, 0.f};
                    z = __builtin_amdgcn_mfma_f32_16x16x32_bf16(kf0, qf[mi][0], z, 0, 0, 0);
                    z = __builtin_amdgcn_mfma_f32_16x16x32_bf16(kf1, qf[mi][1], z, 0, 0, 0);
                    v4s p;
#pragma unroll
                    for (int reg = 0; reg < 4; ++reg) p[reg] = f2bs(fast_exp2(z[reg]));
                    pp[mi][j] = p;
                }
            }

#pragma unroll
            for (int cj = 0; cj < 2; ++cj) {
                v8s pf[2];
#pragma unroll
                for (int mi = 0; mi < 2; ++mi)
                    pf[mi] = __builtin_shufflevector(pp[mi][2 * cj], pp[mi][2 * cj + 1],
                                                     0, 1, 2, 3, 4, 5, 6, 7);
#pragma unroll
                for (int n = 0; n < 4; ++n) {
                    const v8s vf = *reinterpret_cast<const v8s*>(
                        &lV[(n * 16 + l16) * LSV + kt2 * 64 + cj * 32 + quad * 8]);
#pragma unroll
                    for (int mi = 0; mi < 2; ++mi)
                        oacc[mi][n] = __builtin_amdgcn_mfma_f32_16x16x32_bf16(pf[mi], vf, oacc[mi][n], 0, 0, 0);
                }
#pragma unroll
                for (int mi = 0; mi < 2; ++mi)
                    oacc[mi][4] = __builtin_amdgcn_mfma_f32_16x16x32_bf16(pf[mi], ones8, oacc[mi][4], 0, 0, 0);
            }
        }
        __syncthreads();
    }

#pragma unroll
    for (int mi = 0; mi < 2; ++mi) {
        float rdiv[4];
#pragma unroll
        for (int reg = 0; reg < 4; ++reg)
            rdiv[reg] = __builtin_amdgcn_rcpf(oacc[mi][4][reg]);
#pragma unroll
        for (int n = 0; n < 4; ++n)
#pragma unroll
            for (int reg = 0; reg < 4; ++reg) {
                const int qrow = qt * 128 + wid * 32 + mi * 16 + quad * 4 + reg;
                Oat[(size_t)(b * SEQ + qrow) * DMODEL + h * 64 + n * 16 + l16] =
                    f2bs(oacc[mi][n][reg] * rdiv[reg]);
            }
    }
}

// ---------------------------------------------------------------------------
// Output GEMM, m97-style: BM=BN=128, BK=32, unpadded LDS + global_load_lds.
// grid (64, 6). out fp32.
// ---------------------------------------------------------------------------
__global__ __launch_bounds__(256) void out_gemm(
    const short* __restrict__ A, const short* __restrict__ WT,
    const float* __restrict__ bias, float* __restrict__ out)
{
    __shared__ short lA[128 * 32];
    __shared__ short lB[128 * 32];

    const int tid  = threadIdx.x;
    const int lane = tid & 63;
    const int wid  = tid >> 6;
    const int l16  = lane & 15;
    const int quad = lane >> 4;
    const int wm   = wid & 1;
    const int wn   = wid >> 1;
    const int bm   = blockIdx.x;
    const int bn   = blockIdx.y;

    v4f acc[4][4];
#pragma unroll
    for (int i = 0; i < 4; ++i)
#pragma unroll
        for (int j = 0; j < 4; ++j) acc[i][j] = (v4f){0.f, 0.f, 0.f, 0.f};

    const int crow = lane >> 2;
    const int ccol = (lane & 3) << 3;
    const short* Abase = A + (size_t)bm * 128 * DMODEL;
    const short* Bbase = WT + (size_t)bn * 128 * DMODEL;

    for (int kt = 0; kt < 24; ++kt) {
        const int k0 = kt * 32;
#pragma unroll
        for (int c = wid; c < 8; c += 4) {
            gld16(Abase + (size_t)(c * 16 + crow) * DMODEL + k0 + ccol, &lA[c * 512]);
            gld16(Bbase + (size_t)(c * 16 + crow) * DMODEL + k0 + ccol, &lB[c * 512]);
        }
        __syncthreads();

        v8s af[4], bf[4];
#pragma unroll
        for (int i = 0; i < 4; ++i)
            af[i] = *reinterpret_cast<const v8s*>(&lA[(wm * 64 + i * 16 + l16) * 32 + quad * 8]);
#pragma unroll
        for (int j = 0; j < 4; ++j)
            bf[j] = *reinterpret_cast<const v8s*>(&lB[(wn * 64 + j * 16 + l16) * 32 + quad * 8]);
#pragma unroll
        for (int i = 0; i < 4; ++i)
#pragma unroll
            for (int j = 0; j < 4; ++j)
                acc[i][j] = __builtin_amdgcn_mfma_f32_16x16x32_bf16(af[i], bf[j], acc[i][j], 0, 0, 0);
        __syncthreads();
    }

#pragma unroll
    for (int i = 0; i < 4; ++i)
#pragma unroll
        for (int j = 0; j < 4; ++j) {
            const int C = bn * 128 + wn * 64 + j * 16 + l16;
            const float bv = bias[C];
#pragma unroll
            for (int reg = 0; reg < 4; ++reg) {
                const int R = bm * 128 + wm * 64 + i * 16 + quad * 4 + reg;
                out[(size_t)R * DMODEL + C] = acc[i][j][reg] + bv;
            }
        }
}

extern "C" void kernel_launch(void* const* d_in, const int* in_sizes, int n_in,
                              void* d_out, int out_size, void* d_ws, size_t ws_size,
                              hipStream_t stream) {
    const float* q  = (const float*)d_in[0];
    const float* k  = (const float*)d_in[1];
    const float* v  = (const float*)d_in[2];
    const float* Wq = (const float*)d_in[3];
    const float* bq = (const float*)d_in[4];
    const float* Wk = (const float*)d_in[5];
    const float* bk = (const float*)d_in[6];
    const float* Wv = (const float*)d_in[7];
    const float* bv = (const float*)d_in[8];
    const float* Wo = (const float*)d_in[9];
    const float* bo = (const float*)d_in[10];

    short* WqT = (short*)d_ws;                              // 589824
    short* WkT = WqT + 589824;                              // 98304
    short* WvT = WkT + 98304;                               // 98304
    short* WoT = WvT + 98304;                               // 589824
    short* qbf = WoT + 589824;                              // 6291456
    short* Qp  = qbf + 6291456;                             // [b,h,s,d]  6291456
    short* Kp  = Qp + (size_t)BS * HEADS * SEQ * DK;        // [b,g,s,d]  1048576
    short* Vt  = Kp + (size_t)BS * GROUPS * SEQ * DK;       // [b,g,d,s_perm] 1048576
    short* Oat = Vt + (size_t)BS * GROUPS * SEQ * DK;       // [b,s,h*d]  6291456

    convert_q<<<1536, 256, 0, stream>>>(q, qbf);
    wtrans_all<<<dim3(24, 24, 4), 256, 0, stream>>>(Wq, Wk, Wv, Wo, WqT, WkT, WvT, WoT);
    proj_all<<<dim3(64, 8), 256, 0, stream>>>(qbf, k, v, WqT, WkT, WvT,
                                              bq, bk, bv, Qp, Kp, Vt);
    attn_kernel<<<dim3(16, HEADS, BS), 256, 0, stream>>>(Qp, Kp, Vt, Oat);
    out_gemm<<<dim3(64, 6), 256, 0, stream>>>(Oat, WoT, bo, (float*)d_out);
}